// Round 2
// 1920.513 us; speedup vs baseline: 1.0193x; 1.0193x over previous
//
#include <hip/hip_runtime.h>
#include <hip/hip_bf16.h>
#include <cstdint>
#include <cstddef>

// Problem: out[t,o] = sum_d x[t,d] * (qw[o,d]*scale) + qbias[o]*bias_scale
//   x:  [8192, 4096]  fp32
//   qw: [16384, 4096] int32 (int8-valued, exact in bf16)
//   out:[8192, 16384] fp32
// Strategy: convert x->bf16 (rounding), qw->bf16 (exact, unscaled), then
// 256x256x64 8-phase bf16 MFMA GEMM (m201 template: counted vmcnt, LDS
// XOR-swizzle via pre-swizzled global source, setprio MFMA clusters,
// XCD-aware block swizzle).  Scale & bias applied in epilogue.
// Fallback (small ws): previous verified fused-conversion 128^2 GEMM.

typedef __bf16 v8bf  __attribute__((ext_vector_type(8)));
typedef float  f32x4 __attribute__((ext_vector_type(4)));

constexpr int M = 8192;
constexpr int N = 16384;
constexpr int K = 4096;
constexpr int NT = K / 64;          // 64 K-tiles of 64

__device__ __forceinline__ unsigned f2bf(float f) {
  union { float f; unsigned u; } v; v.f = f;
  return (v.u + 0x7fffu + ((v.u >> 16) & 1u)) >> 16;   // RNE, finite inputs
}

// ---------------- conversion kernels (fast path) ----------------

__global__ __launch_bounds__(256) void cvt_x_bf16(const float4* __restrict__ in,
                                                  uint2* __restrict__ out) {
  size_t i = (size_t)blockIdx.x * 256 + threadIdx.x;
  float4 a = in[i];
  uint2 o;
  o.x = f2bf(a.x) | (f2bf(a.y) << 16);
  o.y = f2bf(a.z) | (f2bf(a.w) << 16);
  out[i] = o;
}

__global__ __launch_bounds__(256) void cvt_w_bf16(const int4* __restrict__ in,
                                                  uint2* __restrict__ out) {
  size_t i = (size_t)blockIdx.x * 256 + threadIdx.x;
  int4 a = in[i];
  uint2 o;
  o.x = f2bf((float)a.x) | (f2bf((float)a.y) << 16);   // exact for |v|<=127
  o.y = f2bf((float)a.z) | (f2bf((float)a.w) << 16);
  out[i] = o;
}

// ---------------- 8-phase 256x256x64 GEMM ----------------
// LDS per operand: [buf(2)][khalf(2)] slots of 256rows x 32cols bf16 (16 KiB).
// Slot physical layout: 128 phys-rows x 128 B; logical (r in 0..255, c8 in 0..3):
//   pr = r>>1, seg = ((r&1)*4 + c8) ^ (pr&7)   (XOR swizzle, bijective)
// global_load_lds writes linearly (dest seg P = i*512 + tid); the per-lane
// GLOBAL source is inverse-swizzled so reads use the same involution (rule 21).

#define GLD16(G, L) __builtin_amdgcn_global_load_lds(                        \
    (const __attribute__((address_space(1))) void*)(G),                      \
    (__attribute__((address_space(3))) void*)(L), 16, 0, 0)

template<int CUR, int KH, int MH, bool DOB>
__device__ __forceinline__ void phase_loads(const __bf16* As, const __bf16* Bs,
                                            int aBase, int bBase,
                                            v8bf (&a)[4], v8bf (&b)[4]) {
  if constexpr (DOB) {
#pragma unroll
    for (int j = 0; j < 4; ++j)
      b[j] = *(const v8bf*)(Bs + CUR * 16384 + KH * 8192 + bBase + j * 512);
  }
#pragma unroll
  for (int i = 0; i < 4; ++i)
    a[i] = *(const v8bf*)(As + CUR * 16384 + KH * 8192 + MH * 2048 + aBase + i * 512);
}

template<int MH>
__device__ __forceinline__ void phase_mfma(v8bf (&a)[4], v8bf (&b)[4],
                                           f32x4 (&acc)[8][4]) {
  __builtin_amdgcn_s_setprio(1);
#pragma unroll
  for (int i = 0; i < 4; ++i)
#pragma unroll
    for (int j = 0; j < 4; ++j)
      acc[MH * 4 + i][j] =
          __builtin_amdgcn_mfma_f32_16x16x32_bf16(a[i], b[j], acc[MH * 4 + i][j], 0, 0, 0);
  __builtin_amdgcn_s_setprio(0);
}

// stage one (operand, khalf) half-tile of tile with K-offset KOFF (elements,
// includes kh*32) into LDS [BUF][KH]; 2 x global_load_lds(16B) per thread.
#define STAGE_A(BUF, KH, KOFF) do {                                          \
    GLD16(pA0 + (KOFF), As + (BUF) * 16384 + (KH) * 8192 + wave * 512);      \
    GLD16(pA1 + (KOFF), As + (BUF) * 16384 + (KH) * 8192 + 4096 + wave * 512); \
  } while (0)
#define STAGE_B(BUF, KH, KOFF) do {                                          \
    GLD16(pB0 + (KOFF), Bs + (BUF) * 16384 + (KH) * 8192 + wave * 512);      \
    GLD16(pB1 + (KOFF), Bs + (BUF) * 16384 + (KH) * 8192 + 4096 + wave * 512); \
  } while (0)

#define BAR() __builtin_amdgcn_s_barrier()

// One K-tile = 4 phases (khalf, mhalf).  Stage schedule (WAR-safe, see notes):
//   p1: A(t+1,k1)  p2: B(t+1,k1)  p3: A(t+2,k0)  p4: B(t+2,k0)
// Single counted vmcnt(4) per K-tile: tile t+1 fully resident, 2 half-tiles
// (tile t+2 k0) stay in flight across the tile boundary.
#define TILE_BODY(CUR, NXT, KA, KB) do {                                     \
    phase_loads<CUR, 0, 0, true>(As, Bs, aBase, bBase, a, b);                \
    STAGE_A(NXT, 1, (KA) + 32);                                              \
    BAR();                                                                   \
    phase_mfma<0>(a, b, acc);                                                \
    BAR();                                                                   \
    phase_loads<CUR, 0, 1, false>(As, Bs, aBase, bBase, a, b);               \
    STAGE_B(NXT, 1, (KA) + 32);                                              \
    BAR();                                                                   \
    phase_mfma<1>(a, b, acc);                                                \
    BAR();                                                                   \
    phase_loads<CUR, 1, 0, true>(As, Bs, aBase, bBase, a, b);                \
    STAGE_A(CUR, 0, (KB));                                                   \
    BAR();                                                                   \
    phase_mfma<0>(a, b, acc);                                                \
    BAR();                                                                   \
    phase_loads<CUR, 1, 1, false>(As, Bs, aBase, bBase, a, b);               \
    STAGE_B(CUR, 0, (KB));                                                   \
    BAR();                                                                   \
    phase_mfma<1>(a, b, acc);                                                \
    asm volatile("s_waitcnt vmcnt(4)" ::: "memory");                         \
    BAR();                                                                   \
  } while (0)

__global__ __launch_bounds__(512, 2) void gemm_bt8(const __bf16* __restrict__ A,
                                                   const __bf16* __restrict__ B,
                                                   const int* __restrict__ qbias,
                                                   const float* __restrict__ scale,
                                                   const float* __restrict__ bscale,
                                                   float* __restrict__ C) {
  __shared__ __bf16 As[2 * 2 * 8192];   // 64 KiB
  __shared__ __bf16 Bs[2 * 2 * 8192];   // 64 KiB

  const int t    = threadIdx.x;          // 0..511
  const int wave = t >> 6;               // 0..7
  const int lane = t & 63;
  const int quad = lane >> 4;            // 0..3
  const int l16  = lane & 15;
  const int wr   = wave >> 2;            // 0..1 : M half (128 rows)
  const int wc   = wave & 3;             // 0..3 : N quarter (64 cols)

  // T1: bijective XCD-chunked block swizzle (2048 = 8 * 256)
  const int bid = blockIdx.x;
  const int wgs = ((bid & 7) << 8) | (bid >> 3);
  const int bx  = wgs & 63;              // n-block
  const int by  = wgs >> 6;              // m-block
  const int m0  = by * 256;
  const int n0  = bx * 256;

  // -------- read-side swizzled fragment bases (elements) --------
  // frag (row r = base + i*16 + l16, c8 = quad):
  //   pr&7 == l16>>1 ; seg = ((l16&1)*4 + quad) ^ (l16>>1)   (lane constant)
  const int pseg  = (((l16 & 1) << 2) | quad) ^ (l16 >> 1);
  const int aBase = (wr * 64 + (l16 >> 1)) * 64 + pseg * 8;
  const int bBase = (wc * 32 + (l16 >> 1)) * 64 + pseg * 8;

  // -------- write-side: per-thread inverse-swizzled global source --------
  // dest seg P = i*512 + t ; pr = P>>3, ps = P&7, lseg = ps ^ (pr&7),
  // r = 2*pr + (lseg>>2), c8 = lseg&3.  (i=1 is same r+128, same c8.)
  const int pr0 = t >> 3;
  const int ls0 = (t & 7) ^ (pr0 & 7);
  const int r0  = pr0 * 2 + (ls0 >> 2);
  const int c80 = ls0 & 3;
  const __bf16* pA0 = A + (size_t)(m0 + r0) * K + c80 * 8;
  const __bf16* pA1 = pA0 + (size_t)128 * K;
  const __bf16* pB0 = B + (size_t)(n0 + r0) * K + c80 * 8;
  const __bf16* pB1 = pB0 + (size_t)128 * K;

  f32x4 acc[8][4] = {};
  v8bf a[4], b[4];

  // -------- prologue: tile0 (4 halves) + tile1 k0 (2 halves) --------
  STAGE_A(0, 0, 0);
  STAGE_B(0, 0, 0);
  STAGE_A(0, 1, 32);
  STAGE_B(0, 1, 32);
  STAGE_A(1, 0, 64);
  STAGE_B(1, 0, 64);
  asm volatile("s_waitcnt vmcnt(4)" ::: "memory");   // tile0 resident
  BAR();

  // -------- main loop: 2 K-tiles (8 phases) per iteration --------
  for (int tt = 0; tt < NT; tt += 2) {
    const int ka  = (tt + 1) * 64;                         // tt+1 <= NT-1
    const int kb  = (tt + 2 < NT) ? (tt + 2) * 64 : 0;     // junk-clamped
    TILE_BODY(0, 1, ka, kb);
    const int ka2 = kb;
    const int kb2 = (tt + 3 < NT) ? (tt + 3) * 64 : 0;
    TILE_BODY(1, 0, ka2, kb2);
  }
  asm volatile("s_waitcnt vmcnt(0)" ::: "memory");   // drain tail junk loads

  // -------- epilogue --------
  const float s  = scale[0];
  const float bs = bscale[0];
#pragma unroll
  for (int j = 0; j < 4; ++j) {
    const int col = n0 + wc * 64 + j * 16 + l16;
    const float bias = (float)qbias[col] * bs;
#pragma unroll
    for (int im = 0; im < 8; ++im) {
      const int row = m0 + wr * 128 + im * 16 + quad * 4;
      float* cp = C + (size_t)row * N + col;
#pragma unroll
      for (int r = 0; r < 4; ++r)
        cp[(size_t)r * N] = acc[im][j][r] * s + bias;
    }
  }
}

// ---------------- fallback: fused-conversion 128^2 GEMM (no workspace) ----------------

constexpr int FBM = 128, FBN = 128, FBK = 32;

__device__ __forceinline__ uint4 packf(float4 x, float4 y) {
  uint4 o;
  o.x = f2bf(x.x) | (f2bf(x.y) << 16);
  o.y = f2bf(x.z) | (f2bf(x.w) << 16);
  o.z = f2bf(y.x) | (f2bf(y.y) << 16);
  o.w = f2bf(y.z) | (f2bf(y.w) << 16);
  return o;
}
__device__ __forceinline__ uint4 packi(int4 x, int4 y) {
  uint4 o;
  o.x = f2bf((float)x.x) | (f2bf((float)x.y) << 16);
  o.y = f2bf((float)x.z) | (f2bf((float)x.w) << 16);
  o.z = f2bf((float)y.x) | (f2bf((float)y.y) << 16);
  o.w = f2bf((float)y.z) | (f2bf((float)y.w) << 16);
  return o;
}

__global__ __launch_bounds__(256) void gemm_fused(const float* __restrict__ A32,
                                                  const int* __restrict__ W32,
                                                  const int* __restrict__ qbias,
                                                  const float* __restrict__ scale,
                                                  const float* __restrict__ bscale,
                                                  float* __restrict__ C) {
  __shared__ __bf16 As[FBM * FBK];
  __shared__ __bf16 Bs[FBN * FBK];

  const int t    = threadIdx.x;
  const int wave = t >> 6;
  const int lane = t & 63;
  const int quad = lane >> 4;
  const int l16  = lane & 15;
  const int m0   = blockIdx.y * FBM;
  const int n0   = blockIdx.x * FBN;
  const int wm   = (wave & 1) * 64;
  const int wn   = (wave >> 1) * 64;

  const int srow = t >> 1;
  const int sh   = (t & 1) * 16;
  const float* gA = A32 + (size_t)(m0 + srow) * K + sh;
  const int*   gW = W32 + (size_t)(n0 + srow) * K + sh;
  __bf16* wA = As + srow * FBK + sh;
  __bf16* wB = Bs + srow * FBK + sh;

  f32x4 acc[4][4] = {};

  for (int k0 = 0; k0 < K; k0 += FBK) {
    float4 a0 = *(const float4*)(gA + 0);
    float4 a1 = *(const float4*)(gA + 4);
    float4 a2 = *(const float4*)(gA + 8);
    float4 a3 = *(const float4*)(gA + 12);
    int4 b0 = *(const int4*)(gW + 0);
    int4 b1 = *(const int4*)(gW + 4);
    int4 b2 = *(const int4*)(gW + 8);
    int4 b3 = *(const int4*)(gW + 12);
    gA += FBK; gW += FBK;
    __syncthreads();
    ((uint4*)wA)[0] = packf(a0, a1);
    ((uint4*)wA)[1] = packf(a2, a3);
    ((uint4*)wB)[0] = packi(b0, b1);
    ((uint4*)wB)[1] = packi(b2, b3);
    __syncthreads();

    v8bf a[4], b[4];
#pragma unroll
    for (int i = 0; i < 4; ++i) {
      a[i] = *(const v8bf*)(As + (wm + i * 16 + l16) * FBK + quad * 8);
      b[i] = *(const v8bf*)(Bs + (wn + i * 16 + l16) * FBK + quad * 8);
    }
#pragma unroll
    for (int im = 0; im < 4; ++im)
#pragma unroll
      for (int in = 0; in < 4; ++in)
        acc[im][in] = __builtin_amdgcn_mfma_f32_16x16x32_bf16(a[im], b[in], acc[im][in], 0, 0, 0);
  }

  const float s  = scale[0];
  const float bs = bscale[0];
#pragma unroll
  for (int in = 0; in < 4; ++in) {
    const int col = n0 + wn + in * 16 + l16;
    const float bias = (float)qbias[col] * bs;
#pragma unroll
    for (int im = 0; im < 4; ++im) {
      const int row = m0 + wm + im * 16 + quad * 4;
      float* cp = C + (size_t)row * N + col;
#pragma unroll
      for (int r = 0; r < 4; ++r)
        cp[(size_t)r * N] = acc[im][in][r] * s + bias;
    }
  }
}

extern "C" void kernel_launch(void* const* d_in, const int* in_sizes, int n_in,
                              void* d_out, int out_size, void* d_ws, size_t ws_size,
                              hipStream_t stream) {
  const float* x      = (const float*)d_in[0];   // [M,K] fp32
  const int*   qw     = (const int*)d_in[1];     // [N,K] int32
  const int*   qbias  = (const int*)d_in[2];     // [N]
  const float* scale  = (const float*)d_in[3];
  const float* bscale = (const float*)d_in[4];
  float* out = (float*)d_out;                    // [M,N] fp32

  const size_t needA = (size_t)M * K * sizeof(__bf16);   //  64 MiB
  const size_t needB = (size_t)N * K * sizeof(__bf16);   // 128 MiB

  if (ws_size >= needA + needB) {
    __bf16* wsA = (__bf16*)d_ws;
    __bf16* wsB = wsA + (size_t)M * K;
    cvt_x_bf16<<<(int)((size_t)M * K / (4 * 256)), 256, 0, stream>>>(
        (const float4*)x, (uint2*)wsA);
    cvt_w_bf16<<<(int)((size_t)N * K / (4 * 256)), 256, 0, stream>>>(
        (const int4*)qw, (uint2*)wsB);
    gemm_bt8<<<dim3((M / 256) * (N / 256)), dim3(512), 0, stream>>>(
        wsA, wsB, qbias, scale, bscale, out);
  } else {
    dim3 grid(N / FBN, M / FBM);
    gemm_fused<<<grid, 256, 0, stream>>>(x, qw, qbias, scale, bscale, out);
  }
}